// Round 1
// baseline (414.781 us; speedup 1.0000x reference)
//
#include <hip/hip_runtime.h>
#include <math.h>

#define H 160
#define W 480
#define HW 76800
#define CIMG 256
#define NPTS 120000
#define T9S 12  // t9 row stride (9 used + 3 pad for float4 alignment)

// ws layout (bytes):
//   winner0 @ 0        (76800 * 4 = 307200)
//   winner1 @ 307200
//   winner2 @ 614400
//   t9      @ 921600   (76800 * 12 * 4 = 3686400)  layout [pixel][12]
//   Weff0   @ 4608000  (9*64*4  = 2304)
//   Weff1   @ 4610304  (9*128*4 = 4608)
//   bconst  @ 4614912  (9*4, pad)
//   sa      @ 0        (aliases winner0; winners dead by then)

__global__ __launch_bounds__(256) void scatter_winners(
    const int2* __restrict__ g0, const int2* __restrict__ g1, const int2* __restrict__ g2,
    int* __restrict__ w0, int* __restrict__ w1, int* __restrict__ w2) {
  int j = blockIdx.x * blockDim.x + threadIdx.x;
  if (j >= NPTS) return;
  int2 c;
  c = g0[j];
  if ((unsigned)c.x < W && (unsigned)c.y < H) atomicMax(&w0[c.y * W + c.x], j);
  c = g1[j];
  if ((unsigned)c.x < W && (unsigned)c.y < H) atomicMax(&w1[c.y * W + c.x], j);
  c = g2[j];
  if ((unsigned)c.x < W && (unsigned)c.y < H) atomicMax(&w2[c.y * W + c.x], j);
}

__global__ __launch_bounds__(256) void prep_weights(
    const float* __restrict__ rw0, const float* __restrict__ rw1,
    const float* __restrict__ rb0, const float* __restrict__ rb1,
    const float* __restrict__ sbw,
    float* __restrict__ Weff0, float* __restrict__ Weff1, float* __restrict__ bconst) {
  int t = blockIdx.x * blockDim.x + threadIdx.x;
  if (t < 576) {
    int jj = t / 64, k = t % 64;
    float s = 0.f;
    for (int c = 0; c < 256; ++c) s = fmaf(rw0[c * 64 + k], sbw[(256 + c) * 9 + jj], s);
    Weff0[jj * 64 + k] = s;
  } else if (t < 1728) {
    int tt = t - 576;
    int jj = tt / 128, k = tt % 128;
    float s = 0.f;
    for (int c = 0; c < 256; ++c) s = fmaf(rw1[c * 128 + k], sbw[(256 + c) * 9 + jj], s);
    Weff1[jj * 128 + k] = s;
  } else if (t < 1737) {
    int jj = t - 1728;
    float s = 0.f;
    for (int c = 0; c < 256; ++c) s = fmaf(rb0[c] + rb1[c], sbw[(256 + c) * 9 + jj], s);
    bconst[jj] = s;
  }
}

// t9[p][j] = seg1[p] * sum_c img[c][p] * sbw[c*9+j]   (enhanced-features conv taps)
__global__ __launch_bounds__(256) void t_img_kernel(
    const float* __restrict__ img, const float* __restrict__ seg,
    const float* __restrict__ sbw, float* __restrict__ t9) {
  int p = blockIdx.x * blockDim.x + threadIdx.x;  // exact 76800
  float acc[9];
#pragma unroll
  for (int j = 0; j < 9; ++j) acc[j] = 0.f;
#pragma unroll 8
  for (int c = 0; c < 256; ++c) {
    float v = img[c * HW + p];
    const float* wr = sbw + c * 9;  // wave-uniform -> scalar loads
#pragma unroll
    for (int j = 0; j < 9; ++j) acc[j] = fmaf(v, wr[j], acc[j]);
  }
  float s = seg[HW + p];  // seg_prob[0,1]
  float4 o0 = make_float4(acc[0] * s, acc[1] * s, acc[2] * s, acc[3] * s);
  float4 o1 = make_float4(acc[4] * s, acc[5] * s, acc[6] * s, acc[7] * s);
  float4 o2 = make_float4(acc[8] * s, 0.f, 0.f, 0.f);
  float* dst = t9 + (size_t)p * T9S;
  *(float4*)(dst + 0) = o0;
  *(float4*)(dst + 4) = o1;
  *(float4*)(dst + 8) = o2;
}

// One wave per pixel (8 pixels per wave, sequential). Lanes split channels,
// 9 accumulators, butterfly reduce, lanes 0..8 write t9[p][j] += sum.
#define PIXW 8
__global__ __launch_bounds__(256) void t_vox_kernel(
    const float* __restrict__ vf0, const float* __restrict__ vf1, const float* __restrict__ vf2,
    const int* __restrict__ w0m, const int* __restrict__ w1m, const int* __restrict__ w2m,
    const float* __restrict__ Weff0, const float* __restrict__ Weff1,
    const float* __restrict__ sbw, float* __restrict__ t9) {
  int lane = threadIdx.x & 63;
  int waveId = (blockIdx.x * blockDim.x + threadIdx.x) >> 6;

  // per-lane weight registers (fixed lane->channel map)
  float wg0[9], wg1[2][9], wg2[4][9];
#pragma unroll
  for (int j = 0; j < 9; ++j) wg0[j] = Weff0[j * 64 + lane];
#pragma unroll
  for (int j = 0; j < 9; ++j) {
    wg1[0][j] = Weff1[j * 128 + 2 * lane + 0];
    wg1[1][j] = Weff1[j * 128 + 2 * lane + 1];
  }
#pragma unroll
  for (int i = 0; i < 4; ++i)
#pragma unroll
    for (int j = 0; j < 9; ++j) wg2[i][j] = sbw[(256 + 4 * lane + i) * 9 + j];

  int pix0 = waveId * PIXW;
  for (int q = 0; q < PIXW; ++q) {
    int pix = pix0 + q;
    int w0 = w0m[pix], w1 = w1m[pix], w2 = w2m[pix];
    float acc[9];
#pragma unroll
    for (int j = 0; j < 9; ++j) acc[j] = 0.f;
    if (w0 >= 0) {
      float v = vf0[(size_t)w0 * 64 + lane];
#pragma unroll
      for (int j = 0; j < 9; ++j) acc[j] = fmaf(v, wg0[j], acc[j]);
    }
    if (w1 >= 0) {
      float2 v = *(const float2*)(vf1 + (size_t)w1 * 128 + 2 * lane);
#pragma unroll
      for (int j = 0; j < 9; ++j) {
        acc[j] = fmaf(v.x, wg1[0][j], acc[j]);
        acc[j] = fmaf(v.y, wg1[1][j], acc[j]);
      }
    }
    if (w2 >= 0) {
      float4 v = *(const float4*)(vf2 + (size_t)w2 * 256 + 4 * lane);
#pragma unroll
      for (int j = 0; j < 9; ++j) {
        acc[j] = fmaf(v.x, wg2[0][j], acc[j]);
        acc[j] = fmaf(v.y, wg2[1][j], acc[j]);
        acc[j] = fmaf(v.z, wg2[2][j], acc[j]);
        acc[j] = fmaf(v.w, wg2[3][j], acc[j]);
      }
    }
    // butterfly reduce all 9 across 64 lanes
#pragma unroll
    for (int j = 0; j < 9; ++j) {
      float v = acc[j];
      v += __shfl_xor(v, 1);
      v += __shfl_xor(v, 2);
      v += __shfl_xor(v, 4);
      v += __shfl_xor(v, 8);
      v += __shfl_xor(v, 16);
      v += __shfl_xor(v, 32);
      acc[j] = v;
    }
    if (lane < 9) {
      float v = acc[0];
#pragma unroll
      for (int j = 1; j < 9; ++j) v = (lane == j) ? acc[j] : v;
      t9[(size_t)pix * T9S + lane] += v;
    }
  }
}

// attention = sigmoid(sb_b + sum over valid taps (t9 + bconst)); sa = attention * seg1
__global__ __launch_bounds__(256) void conv_sig_kernel(
    const float* __restrict__ t9, const float* __restrict__ bconst,
    const float* __restrict__ sbb, const float* __restrict__ seg,
    float* __restrict__ sa) {
  int p = blockIdx.x * blockDim.x + threadIdx.x;  // exact 76800
  int y = p / W, x = p - y * W;
  float s = sbb[0];
#pragma unroll
  for (int dy = -1; dy <= 1; ++dy) {
#pragma unroll
    for (int dx = -1; dx <= 1; ++dx) {
      int yy = y + dy, xx = x + dx;
      if ((unsigned)yy < H && (unsigned)xx < W) {
        int j = (dy + 1) * 3 + (dx + 1);
        s += t9[(size_t)(yy * W + xx) * T9S + j] + bconst[j];
      }
    }
  }
  float att = 1.f / (1.f + expf(-s));
  sa[p] = att * seg[HW + p];
}

// out[c][p] = img[c][p] * sa[p]   (float4 over 19.66M elems)
__global__ __launch_bounds__(256) void final_mul_kernel(
    const float* __restrict__ img, const float* __restrict__ sa, float* __restrict__ out) {
  int i = blockIdx.x * blockDim.x + threadIdx.x;  // float4 index, exact 4915200
  int e = i * 4;
  int p = e % HW;  // 76800 % 4 == 0 so float4 stays within one channel row
  float4 v = *(const float4*)(img + e);
  float4 g = *(const float4*)(sa + p);
  float4 o = make_float4(v.x * g.x, v.y * g.y, v.z * g.z, v.w * g.w);
  *(float4*)(out + e) = o;
}

extern "C" void kernel_launch(void* const* d_in, const int* in_sizes, int n_in,
                              void* d_out, int out_size, void* d_ws, size_t ws_size,
                              hipStream_t stream) {
  const float* img = (const float*)d_in[0];
  const float* seg = (const float*)d_in[1];
  // setup_inputs() dict order interleaves voxel_feat{i}/img_grid{i}; detect defensively.
  int iV0 = 2, iG0 = 3, iV1 = 4, iG1 = 5, iV2 = 6, iG2 = 7;
  if (in_sizes[3] != 2 * NPTS) {  // grouped (reference-arg) order fallback
    iV0 = 2; iV1 = 3; iV2 = 4; iG0 = 5; iG1 = 6; iG2 = 7;
  }
  const float* vf0 = (const float*)d_in[iV0];
  const float* vf1 = (const float*)d_in[iV1];
  const float* vf2 = (const float*)d_in[iV2];
  const int2* g0 = (const int2*)d_in[iG0];
  const int2* g1 = (const int2*)d_in[iG1];
  const int2* g2 = (const int2*)d_in[iG2];
  const float* rw0 = (const float*)d_in[8];
  const float* rb0 = (const float*)d_in[9];
  const float* rw1 = (const float*)d_in[10];
  const float* rb1 = (const float*)d_in[11];
  const float* sbw = (const float*)d_in[12];
  const float* sbb = (const float*)d_in[13];

  char* ws = (char*)d_ws;
  int* w0m = (int*)(ws + 0);
  int* w1m = (int*)(ws + 307200);
  int* w2m = (int*)(ws + 614400);
  float* t9 = (float*)(ws + 921600);
  float* Weff0 = (float*)(ws + 4608000);
  float* Weff1 = (float*)(ws + 4610304);
  float* bconst = (float*)(ws + 4614912);
  float* sa = (float*)(ws + 0);  // aliases winner maps (dead after t_vox)

  float* out = (float*)d_out;

  hipMemsetAsync(w0m, 0xFF, 3 * 307200, stream);  // winners = -1
  prep_weights<<<7, 256, 0, stream>>>(rw0, rw1, rb0, rb1, sbw, Weff0, Weff1, bconst);
  scatter_winners<<<(NPTS + 255) / 256, 256, 0, stream>>>(g0, g1, g2, w0m, w1m, w2m);
  t_img_kernel<<<HW / 256, 256, 0, stream>>>(img, seg, sbw, t9);
  t_vox_kernel<<<HW / (4 * PIXW), 256, 0, stream>>>(vf0, vf1, vf2, w0m, w1m, w2m,
                                                    Weff0, Weff1, sbw, t9);
  conv_sig_kernel<<<HW / 256, 256, 0, stream>>>(t9, bconst, sbb, seg, sa);
  final_mul_kernel<<<(out_size / 4) / 256, 256, 0, stream>>>(img, sa, out);
}

// Round 2
// 379.791 us; speedup vs baseline: 1.0921x; 1.0921x over previous
//
#include <hip/hip_runtime.h>
#include <math.h>

#define H 160
#define W 480
#define HW 76800
#define NPTS 120000
#define NSLICE 5

// ws layout (bytes):
//   winner0 @ 0        (76800*4)
//   winner1 @ 307200
//   winner2 @ 614400
//   t9      @ 921600   5 slices x [pixel][12] floats = 18,432,000 B
//   Weff0   @ 19353600 (64*12*4  = 3072)   layout [c][12]
//   Weff1   @ 19356672 (128*12*4 = 6144)   layout [c][12]
//   bconst  @ 19362816 (9*4)
//   sa      @ 0        (aliases winner0; winners dead after t9_kernel)
#define OFF_W1M 307200
#define OFF_W2M 614400
#define OFF_T9  921600
#define OFF_WE0 19353600
#define OFF_WE1 19356672
#define OFF_BC  19362816

__global__ __launch_bounds__(256) void scatter_winners(
    const int2* __restrict__ g0, const int2* __restrict__ g1, const int2* __restrict__ g2,
    int* __restrict__ w0, int* __restrict__ w1, int* __restrict__ w2) {
  int j = blockIdx.x * blockDim.x + threadIdx.x;
  if (j >= NPTS) return;
  int2 c;
  c = g0[j];
  if ((unsigned)c.x < W && (unsigned)c.y < H) atomicMax(&w0[c.y * W + c.x], j);
  c = g1[j];
  if ((unsigned)c.x < W && (unsigned)c.y < H) atomicMax(&w1[c.y * W + c.x], j);
  c = g2[j];
  if ((unsigned)c.x < W && (unsigned)c.y < H) atomicMax(&w2[c.y * W + c.x], j);
}

// Weff layouts are [in_channel][12] (stride 12 floats, 9 used) so the
// per-pixel kernel walks channels contiguously with wave-uniform addresses.
__global__ __launch_bounds__(256) void prep_weights(
    const float* __restrict__ rw0, const float* __restrict__ rw1,
    const float* __restrict__ rb0, const float* __restrict__ rb1,
    const float* __restrict__ sbw,
    float* __restrict__ Weff0, float* __restrict__ Weff1, float* __restrict__ bconst) {
  int t = blockIdx.x * blockDim.x + threadIdx.x;
  if (t < 576) {
    int jj = t / 64, k = t % 64;
    float s = 0.f;
    for (int c = 0; c < 256; ++c) s = fmaf(rw0[c * 64 + k], sbw[(256 + c) * 9 + jj], s);
    Weff0[k * 12 + jj] = s;
  } else if (t < 1728) {
    int tt = t - 576;
    int jj = tt / 128, k = tt % 128;
    float s = 0.f;
    for (int c = 0; c < 256; ++c) s = fmaf(rw1[c * 128 + k], sbw[(256 + c) * 9 + jj], s);
    Weff1[k * 12 + jj] = s;
  } else if (t < 1737) {
    int jj = t - 1728;
    float s = 0.f;
    for (int c = 0; c < 256; ++c) s = fmaf(rb0[c] + rb1[c], sbw[(256 + c) * 9 + jj], s);
    bconst[jj] = s;
  }
}

// Thread-per-pixel, channel slice per blockIdx.y. No cross-lane ops.
// slice 0: img c[0,128)   slice 1: img c[128,256)   (both scaled by seg)
// slice 2: vox L0 (64ch) + L1 (128ch)
// slice 3: vox L2 c[0,128)   slice 4: vox L2 c[128,256)
__global__ __launch_bounds__(256) void t9_kernel(
    const float* __restrict__ img, const float* __restrict__ seg,
    const float* __restrict__ vf0, const float* __restrict__ vf1,
    const float* __restrict__ vf2,
    const int* __restrict__ w0m, const int* __restrict__ w1m, const int* __restrict__ w2m,
    const float* __restrict__ We0, const float* __restrict__ We1,
    const float* __restrict__ sbw, float* __restrict__ t9) {
  int p = blockIdx.x * 256 + threadIdx.x;  // exact 76800
  int slice = blockIdx.y;
  float acc[9];
#pragma unroll
  for (int j = 0; j < 9; ++j) acc[j] = 0.f;

  if (slice < 2) {
    int c0 = slice * 128;
#pragma unroll 8
    for (int cc = 0; cc < 128; ++cc) {
      int c = c0 + cc;
      float v = img[c * HW + p];           // coalesced vector load
      const float* wr = sbw + c * 9;       // wave-uniform -> s_load
#pragma unroll
      for (int j = 0; j < 9; ++j) acc[j] = fmaf(v, wr[j], acc[j]);
    }
    float s = seg[HW + p];
#pragma unroll
    for (int j = 0; j < 9; ++j) acc[j] *= s;
  } else if (slice == 2) {
    int w0 = w0m[p];
    if (w0 >= 0) {
      const float4* r = (const float4*)(vf0 + (size_t)w0 * 64);
#pragma unroll 8
      for (int i = 0; i < 16; ++i) {
        float4 v = r[i];                   // per-thread row walk (L1 reuse)
        const float* wc = We0 + i * 48;    // wave-uniform -> s_load
#pragma unroll
        for (int j = 0; j < 9; ++j) {
          acc[j] = fmaf(v.x, wc[j], acc[j]);
          acc[j] = fmaf(v.y, wc[12 + j], acc[j]);
          acc[j] = fmaf(v.z, wc[24 + j], acc[j]);
          acc[j] = fmaf(v.w, wc[36 + j], acc[j]);
        }
      }
    }
    int w1 = w1m[p];
    if (w1 >= 0) {
      const float4* r = (const float4*)(vf1 + (size_t)w1 * 128);
#pragma unroll 8
      for (int i = 0; i < 32; ++i) {
        float4 v = r[i];
        const float* wc = We1 + i * 48;
#pragma unroll
        for (int j = 0; j < 9; ++j) {
          acc[j] = fmaf(v.x, wc[j], acc[j]);
          acc[j] = fmaf(v.y, wc[12 + j], acc[j]);
          acc[j] = fmaf(v.z, wc[24 + j], acc[j]);
          acc[j] = fmaf(v.w, wc[36 + j], acc[j]);
        }
      }
    }
  } else {
    int w2 = w2m[p];
    if (w2 >= 0) {
      int cbase = (slice - 3) * 128;
      const float4* r = (const float4*)(vf2 + (size_t)w2 * 256 + cbase);
#pragma unroll 8
      for (int i = 0; i < 32; ++i) {
        float4 v = r[i];
        const float* wc = sbw + (256 + cbase + 4 * i) * 9;  // stride-9 direct
#pragma unroll
        for (int j = 0; j < 9; ++j) {
          acc[j] = fmaf(v.x, wc[j], acc[j]);
          acc[j] = fmaf(v.y, wc[9 + j], acc[j]);
          acc[j] = fmaf(v.z, wc[18 + j], acc[j]);
          acc[j] = fmaf(v.w, wc[27 + j], acc[j]);
        }
      }
    }
  }

  float* dst = t9 + ((size_t)slice * HW + p) * 12;
  *(float4*)(dst + 0) = make_float4(acc[0], acc[1], acc[2], acc[3]);
  *(float4*)(dst + 4) = make_float4(acc[4], acc[5], acc[6], acc[7]);
  *(float4*)(dst + 8) = make_float4(acc[8], 0.f, 0.f, 0.f);
}

// attention = sigmoid(sb_b + sum over valid taps (sum_slices t9 + bconst)); sa = att*seg1
__global__ __launch_bounds__(256) void conv_sig_kernel(
    const float* __restrict__ t9, const float* __restrict__ bconst,
    const float* __restrict__ sbb, const float* __restrict__ seg,
    float* __restrict__ sa) {
  int p = blockIdx.x * blockDim.x + threadIdx.x;  // exact 76800
  int y = p / W, x = p - y * W;
  float s = sbb[0];
#pragma unroll
  for (int dy = -1; dy <= 1; ++dy) {
#pragma unroll
    for (int dx = -1; dx <= 1; ++dx) {
      int yy = y + dy, xx = x + dx;
      if ((unsigned)yy < H && (unsigned)xx < W) {
        int j = (dy + 1) * 3 + (dx + 1);
        size_t q = (size_t)(yy * W + xx) * 12 + j;
        s += bconst[j];
#pragma unroll
        for (int b = 0; b < NSLICE; ++b) s += t9[(size_t)b * HW * 12 + q];
      }
    }
  }
  float att = 1.f / (1.f + expf(-s));
  sa[p] = att * seg[HW + p];
}

// out[c][p] = img[c][p] * sa[p]   (float4 over 19.66M elems)
__global__ __launch_bounds__(256) void final_mul_kernel(
    const float* __restrict__ img, const float* __restrict__ sa, float* __restrict__ out) {
  int i = blockIdx.x * blockDim.x + threadIdx.x;  // float4 index, exact 4915200
  int e = i * 4;
  int p = e % HW;  // 76800 % 4 == 0 so float4 stays within one channel row
  float4 v = *(const float4*)(img + e);
  float4 g = *(const float4*)(sa + p);
  float4 o = make_float4(v.x * g.x, v.y * g.y, v.z * g.z, v.w * g.w);
  *(float4*)(out + e) = o;
}

extern "C" void kernel_launch(void* const* d_in, const int* in_sizes, int n_in,
                              void* d_out, int out_size, void* d_ws, size_t ws_size,
                              hipStream_t stream) {
  const float* img = (const float*)d_in[0];
  const float* seg = (const float*)d_in[1];
  // setup_inputs() dict order interleaves voxel_feat{i}/img_grid{i}; detect defensively.
  int iV0 = 2, iG0 = 3, iV1 = 4, iG1 = 5, iV2 = 6, iG2 = 7;
  if (in_sizes[3] != 2 * NPTS) {  // grouped (reference-arg) order fallback
    iV0 = 2; iV1 = 3; iV2 = 4; iG0 = 5; iG1 = 6; iG2 = 7;
  }
  const float* vf0 = (const float*)d_in[iV0];
  const float* vf1 = (const float*)d_in[iV1];
  const float* vf2 = (const float*)d_in[iV2];
  const int2* g0 = (const int2*)d_in[iG0];
  const int2* g1 = (const int2*)d_in[iG1];
  const int2* g2 = (const int2*)d_in[iG2];
  const float* rw0 = (const float*)d_in[8];
  const float* rb0 = (const float*)d_in[9];
  const float* rw1 = (const float*)d_in[10];
  const float* rb1 = (const float*)d_in[11];
  const float* sbw = (const float*)d_in[12];
  const float* sbb = (const float*)d_in[13];

  char* ws = (char*)d_ws;
  int* w0m = (int*)(ws + 0);
  int* w1m = (int*)(ws + OFF_W1M);
  int* w2m = (int*)(ws + OFF_W2M);
  float* t9 = (float*)(ws + OFF_T9);
  float* Weff0 = (float*)(ws + OFF_WE0);
  float* Weff1 = (float*)(ws + OFF_WE1);
  float* bconst = (float*)(ws + OFF_BC);
  float* sa = (float*)(ws + 0);  // aliases winner maps (dead after t9_kernel)

  float* out = (float*)d_out;

  hipMemsetAsync(w0m, 0xFF, 3 * 307200, stream);  // winners = -1
  prep_weights<<<7, 256, 0, stream>>>(rw0, rw1, rb0, rb1, sbw, Weff0, Weff1, bconst);
  scatter_winners<<<(NPTS + 255) / 256, 256, 0, stream>>>(g0, g1, g2, w0m, w1m, w2m);
  dim3 tg(HW / 256, NSLICE);
  t9_kernel<<<tg, 256, 0, stream>>>(img, seg, vf0, vf1, vf2, w0m, w1m, w2m,
                                    Weff0, Weff1, sbw, t9);
  conv_sig_kernel<<<HW / 256, 256, 0, stream>>>(t9, bconst, sbb, seg, sa);
  final_mul_kernel<<<(out_size / 4) / 256, 256, 0, stream>>>(img, sa, out);
}